// Round 7
// baseline (1715.310 us; speedup 1.0000x reference)
//
#include <hip/hip_runtime.h>

// Problem constants
constexpr int NN  = 131072;   // nodes
constexpr int NE  = 2097152;  // edges
constexpr int HD  = 128;      // hidden
constexpr int NG  = 8192;     // graphs
constexpr int NA  = 28;       // atom types
constexpr int NL  = 4;        // layers

// Feature layout: slice-major [8][NN][16] bf16 (slice = col/16; 4 MB/slice = per-XCD L2)
constexpr size_t SL16 = (size_t)NN * 16;   // ushorts per slice
constexpr size_t SLU  = (size_t)NN * 8;    // uints per slice

// CSR bucketing
constexpr int NB   = 256;     // buckets
constexpr int BSH  = 9;       // dst>>9 -> bucket (512 nodes/bucket)
constexpr int BNOD = 512;     // nodes per bucket
constexpr int CAP  = 10240;   // slots per bucket (mean 8192 + 22 sigma)

// ---------------- workspace layout (bytes) ----------------
constexpr size_t SZ_FB   = (size_t)NN * HD * 2;          // 32 MiB bf16 feature buf
constexpr size_t OFF_XB   = 0;
constexpr size_t OFF_YB   = OFF_XB + SZ_FB;
constexpr size_t OFF_CB   = OFF_YB + SZ_FB;              // aggregated C (slice-major)
constexpr size_t OFF_ESRC = OFF_CB + SZ_FB;
constexpr size_t OFF_DEG  = OFF_ESRC + (size_t)NE * 4;
constexpr size_t OFF_GCNT = OFF_DEG + (size_t)NN * 4;
constexpr size_t OFF_ROW  = OFF_GCNT + (size_t)NG * 4;
constexpr size_t OFF_IDEG = OFF_ROW + (size_t)NN * 4;
constexpr size_t OFF_IGC  = OFF_IDEG + (size_t)NN * 4;
constexpr size_t OFF_BSUM = OFF_IGC + (size_t)NG * 4;
constexpr size_t OFF_COFF = OFF_BSUM + 512;
constexpr size_t OFF_WC   = OFF_COFF + 512;
constexpr size_t OFF_WNT  = OFF_WC + 512;                // bf16 W transposed [L][128][256]
constexpr size_t OFF_EBUF = OFF_WNT + (size_t)NL * HD * 256 * 2;
constexpr size_t OFF_GCUR = OFF_EBUF + (size_t)NB * CAP * 4;
constexpr size_t OFF_WET  = OFF_GCUR + (size_t)NB * 4;   // bf16 W_emb^T [128][32]

// ---------------- bf16 helpers ----------------
__device__ __forceinline__ float blo(uint x) { return __uint_as_float(x << 16); }
__device__ __forceinline__ float bhi(uint x) { return __uint_as_float(x & 0xFFFF0000u); }
__device__ __forceinline__ unsigned short f2b(float f) {
  uint u = __float_as_uint(f);
  return (unsigned short)((u + 0x7FFFu + ((u >> 16) & 1u)) >> 16);
}
__device__ __forceinline__ uint pack2(float a, float b) {
  uint ua = __float_as_uint(a), ub = __float_as_uint(b);
  uint lo = (ua + 0x7FFFu + ((ua >> 16) & 1u)) >> 16;
  uint hi = (ub + 0x7FFFu + ((ub >> 16) & 1u)) & 0xFFFF0000u;
  return lo | hi;
}

typedef __attribute__((ext_vector_type(8))) short bf16x8;
typedef __attribute__((ext_vector_type(4))) float f32x4;

// ---------------- CSR build: bucketed ----------------
__global__ void k_binit(int* __restrict__ gcur) {
  int b = threadIdx.x;           // 256
  gcur[b] = b * CAP;
}

// partition edges into NB buckets by dst>>BSH; packed = (dst&511)<<17 | src
__global__ __launch_bounds__(256) void k_bin(const int* __restrict__ src,
                                             const int* __restrict__ dst,
                                             int* __restrict__ gcur,
                                             uint* __restrict__ ebuf) {
  __shared__ int cnt[NB];
  __shared__ int gbase[NB];
  int t = threadIdx.x;
  cnt[t] = 0;
  int es[16], ed[16];
  int base = blockIdx.x * 4096 + t;
#pragma unroll
  for (int j = 0; j < 16; j++) {
    es[j] = src[base + j * 256];
    ed[j] = dst[base + j * 256];
  }
  __syncthreads();
#pragma unroll
  for (int j = 0; j < 16; j++) atomicAdd(&cnt[ed[j] >> BSH], 1);
  __syncthreads();
  int c = cnt[t];
  if (c > 0) gbase[t] = atomicAdd(&gcur[t], c);
  cnt[t] = 0;
  __syncthreads();
#pragma unroll
  for (int j = 0; j < 16; j++) {
    int b = ed[j] >> BSH;
    int r = atomicAdd(&cnt[b], 1);
    ebuf[(size_t)gbase[b] + r] = ((uint)(ed[j] & (BNOD - 1)) << 17) | (uint)es[j];
  }
}

// per-bucket degree histogram (LDS), coalesced deg writes, no global atomics
__global__ __launch_bounds__(256) void k_deg(const int* __restrict__ gcur,
                                             const uint* __restrict__ ebuf,
                                             int* __restrict__ deg) {
  __shared__ int h[BNOD];
  int b = blockIdx.x, t = threadIdx.x;
  h[t] = 0; h[t + 256] = 0;
  int n = gcur[b] - b * CAP;
  __syncthreads();
  const uint* eb = ebuf + (size_t)b * CAP;
  for (int i = t; i < n; i += 256) atomicAdd(&h[eb[i] >> 17], 1);
  __syncthreads();
  deg[b * BNOD + t] = h[t];
  deg[b * BNOD + t + 256] = h[t + 256];
}

__global__ void k_scan1(const int* __restrict__ deg, int* __restrict__ bsum) {
  __shared__ int s[256];
  int b = blockIdx.x, t = threadIdx.x;
  const int4* p = (const int4*)(deg + (size_t)b * 1024);
  int4 v = p[t];
  s[t] = v.x + v.y + v.z + v.w;
  __syncthreads();
  for (int o = 128; o > 0; o >>= 1) {
    if (t < o) s[t] += s[t + o];
    __syncthreads();
  }
  if (t == 0) bsum[b] = s[0];
}

__global__ void k_scan2(const int* __restrict__ bsum, int* __restrict__ coff) {
  __shared__ int s[128];
  int t = threadIdx.x;
  int mine = bsum[t];
  s[t] = mine;
  __syncthreads();
  for (int o = 1; o < 128; o <<= 1) {
    int v = (t >= o) ? s[t - o] : 0;
    __syncthreads();
    s[t] += v;
    __syncthreads();
  }
  coff[t] = s[t] - mine;  // exclusive
}

__global__ void k_scan3(const int* __restrict__ deg, const int* __restrict__ coff,
                        int* __restrict__ row_start, float* __restrict__ inv_deg) {
  __shared__ int s[256];
  int b = blockIdx.x, t = threadIdx.x;
  int base = b * 1024 + t * 4;
  const int4* p = (const int4*)(deg + base);
  int4 d = *p;
  int lsum = d.x + d.y + d.z + d.w;
  s[t] = lsum;
  __syncthreads();
  for (int o = 1; o < 256; o <<= 1) {
    int v = (t >= o) ? s[t - o] : 0;
    __syncthreads();
    s[t] += v;
    __syncthreads();
  }
  int pre = coff[b] + s[t] - lsum;
  int r0 = pre, r1 = r0 + d.x, r2 = r1 + d.y, r3 = r2 + d.z;
  row_start[base] = r0;  row_start[base + 1] = r1;
  row_start[base + 2] = r2;  row_start[base + 3] = r3;
  inv_deg[base]     = 1.0f / fmaxf((float)d.x, 1.0f);
  inv_deg[base + 1] = 1.0f / fmaxf((float)d.y, 1.0f);
  inv_deg[base + 2] = 1.0f / fmaxf((float)d.z, 1.0f);
  inv_deg[base + 3] = 1.0f / fmaxf((float)d.w, 1.0f);
}

// per-bucket placement: LDS cursors, esrc writes land in a 32KB window
__global__ __launch_bounds__(256) void k_place2(const int* __restrict__ gcur,
                                                const uint* __restrict__ ebuf,
                                                const int* __restrict__ row_start,
                                                int* __restrict__ esrc) {
  __shared__ int cur[BNOD];
  int b = blockIdx.x, t = threadIdx.x;
  cur[t] = row_start[b * BNOD + t];
  cur[t + 256] = row_start[b * BNOD + t + 256];
  int n = gcur[b] - b * CAP;
  __syncthreads();
  const uint* eb = ebuf + (size_t)b * CAP;
  for (int i = t; i < n; i += 256) {
    uint p = eb[i];
    int r = atomicAdd(&cur[p >> 17], 1);
    esrc[r] = (int)(p & 0x1FFFFu);
  }
}

__global__ void k_ghist(const int* __restrict__ gid, int* __restrict__ gcnt) {
  int i = blockIdx.x * blockDim.x + threadIdx.x;
  if (i < NN) atomicAdd(&gcnt[gid[i]], 1);
}

__global__ void k_ginit(const int* __restrict__ gcnt, float* __restrict__ inv_gcnt,
                        float* __restrict__ out, const float* __restrict__ b_pred) {
  int g = blockIdx.x * blockDim.x + threadIdx.x;
  if (g < NG) {
    inv_gcnt[g] = 1.0f / fmaxf((float)gcnt[g], 1.0f);
    out[g] = b_pred[0];
  }
}

// ---------------- weight prep ----------------
// Wnt[l][c][k] = bf16(W_node[l][k][c])
__global__ void k_wprep(const float* __restrict__ Wn, unsigned short* __restrict__ Wnt) {
  int i = blockIdx.x * 256 + threadIdx.x;   // L*256*128 total
  int l = i >> 15;
  int k = (i >> 7) & 255;
  int c = i & 127;
  float v = Wn[((size_t)l * 256 + k) * HD + c];
  Wnt[((size_t)l * HD + c) * 256 + k] = f2b(v);
}

// Wet[c][k] = bf16(W_emb[k][c]), k padded 28->32 with zeros
__global__ void k_weprep(const float* __restrict__ We, unsigned short* __restrict__ Wet) {
  int i = blockIdx.x * 256 + threadIdx.x;   // 128*32 = 4096 total
  int col = i >> 5, k = i & 31;
  Wet[i] = (k < NA) ? f2b(We[(size_t)k * HD + col]) : (unsigned short)0;
}

// ---------------- embedding (MFMA): Xs = bf16(h @ W_emb), slice-major out -------
__global__ __launch_bounds__(256) void k_embed(const float* __restrict__ h,
                                               const unsigned short* __restrict__ Wet,
                                               unsigned short* __restrict__ Xs) {
  int t = threadIdx.x;
  int lane = t & 63, w = t >> 6;
  int wr = w >> 1, wc = w & 1;
  int row0 = blockIdx.x * 64 + wr * 32;
  int col0 = wc * 64;
  int fr = lane & 15;
  int fk = (lane >> 4) * 8;

  f32x4 acc[2][4] = {};
  bf16x8 a[2];
#pragma unroll
  for (int rt = 0; rt < 2; rt++) {
    int row = row0 + rt * 16 + fr;
    const float* hp = h + (size_t)row * NA + fk;
    float4 p = *(const float4*)hp;                    // k = fk..fk+3 (always < 28)
    float4 q = make_float4(0.f, 0.f, 0.f, 0.f);
    if (fk < 24) q = *(const float4*)(hp + 4);        // k = fk+4..fk+7; fk==24 -> pad 0
    a[rt][0] = (short)f2b(p.x); a[rt][1] = (short)f2b(p.y);
    a[rt][2] = (short)f2b(p.z); a[rt][3] = (short)f2b(p.w);
    a[rt][4] = (short)f2b(q.x); a[rt][5] = (short)f2b(q.y);
    a[rt][6] = (short)f2b(q.z); a[rt][7] = (short)f2b(q.w);
  }
#pragma unroll
  for (int ct = 0; ct < 4; ct++) {
    int col = col0 + ct * 16 + fr;
    bf16x8 b = *(const bf16x8*)(Wet + (size_t)col * 32 + fk);
#pragma unroll
    for (int rt = 0; rt < 2; rt++)
      acc[rt][ct] = __builtin_amdgcn_mfma_f32_16x16x32_bf16(a[rt], b, acc[rt][ct], 0, 0, 0);
  }
  int oc = lane & 15, orb = (lane >> 4) * 4;
#pragma unroll
  for (int rt = 0; rt < 2; rt++) {
#pragma unroll
    for (int ct = 0; ct < 4; ct++) {
      int slice = wc * 4 + ct;
#pragma unroll
      for (int r = 0; r < 4; r++) {
        int row = row0 + rt * 16 + orb + r;
        Xs[(size_t)slice * SL16 + (size_t)row * 16 + oc] = f2b(acc[rt][ct][r]);
      }
    }
  }
}

// ---------------- aggregation, XCD-sliced: Cs[s][v] = mean_{u->v} Hs[s][u] -------
// slice s = bid&7 pins to one XCD (round-robin dispatch); slice = 4MB = its L2.
// wave: 8 edges x 8 col-pairs per load; 2 nodes in flight (4 loads); shfl reduce.
__global__ __launch_bounds__(256) void k_aggs(const uint* __restrict__ Hs,
                                              const int* __restrict__ row_start,
                                              const int* __restrict__ deg,
                                              const int* __restrict__ esrc,
                                              const float* __restrict__ inv_deg,
                                              uint* __restrict__ Cs) {
  int s = blockIdx.x & 7, chunk = blockIdx.x >> 3;
  int lane = threadIdx.x & 63, w = threadIdx.x >> 6;
  int eg = lane >> 3, c = lane & 7;
  const uint* H = Hs + (size_t)s * SLU;
  uint* C = Cs + (size_t)s * SLU;
  int v0 = chunk * 512 + w * 128;

  for (int i = 0; i < 128; i += 2) {
    int va = v0 + i, vb = va + 1;
    int rsa = __builtin_amdgcn_readfirstlane(row_start[va]);
    int da  = __builtin_amdgcn_readfirstlane(deg[va]);
    int rsb = __builtin_amdgcn_readfirstlane(row_start[vb]);
    int db  = __builtin_amdgcn_readfirstlane(deg[vb]);
    float a0 = 0.f, a1 = 0.f, b0 = 0.f, b1 = 0.f;
    int ea = 0, eb = 0;
    while (ea < da || eb < db) {
      uint xa0 = 0, xa1 = 0, xb0 = 0, xb1 = 0;
      if (ea + eg < da) {
        int idx = __builtin_nontemporal_load(esrc + rsa + ea + eg);
        xa0 = H[(size_t)idx * 8 + c];
      }
      if (ea + 8 + eg < da) {
        int idx = __builtin_nontemporal_load(esrc + rsa + ea + 8 + eg);
        xa1 = H[(size_t)idx * 8 + c];
      }
      if (eb + eg < db) {
        int idx = __builtin_nontemporal_load(esrc + rsb + eb + eg);
        xb0 = H[(size_t)idx * 8 + c];
      }
      if (eb + 8 + eg < db) {
        int idx = __builtin_nontemporal_load(esrc + rsb + eb + 8 + eg);
        xb1 = H[(size_t)idx * 8 + c];
      }
      a0 += blo(xa0) + blo(xa1);  a1 += bhi(xa0) + bhi(xa1);
      b0 += blo(xb0) + blo(xb1);  b1 += bhi(xb0) + bhi(xb1);
      ea += 16;  eb += 16;
    }
    // reduce across the 8 edge-groups
    a0 += __shfl_xor(a0, 8, 64);  a0 += __shfl_xor(a0, 16, 64);  a0 += __shfl_xor(a0, 32, 64);
    a1 += __shfl_xor(a1, 8, 64);  a1 += __shfl_xor(a1, 16, 64);  a1 += __shfl_xor(a1, 32, 64);
    b0 += __shfl_xor(b0, 8, 64);  b0 += __shfl_xor(b0, 16, 64);  b0 += __shfl_xor(b0, 32, 64);
    b1 += __shfl_xor(b1, 8, 64);  b1 += __shfl_xor(b1, 16, 64);  b1 += __shfl_xor(b1, 32, 64);
    if (eg == 0) {
      float ida = inv_deg[va], idb = inv_deg[vb];
      __builtin_nontemporal_store(pack2(a0 * ida, a1 * ida), C + (size_t)va * 8 + c);
      __builtin_nontemporal_store(pack2(b0 * idb, b1 * idb), C + (size_t)vb * 8 + c);
    }
  }
}

// ---------------- NodeApply (MFMA): Os = bf16(relu([Hs||Cs]@W + b)*snorm + Hs) ---
// block: 256 rows, 4 waves x (64 rows x 128 cols); full Wt staged once in LDS in
// frag-major layout (lane-contiguous -> conflict-free); single barrier.
__global__ __launch_bounds__(256) void k_apply2(const unsigned short* __restrict__ Hs,
                                                const unsigned short* __restrict__ Csb,
                                                unsigned short* __restrict__ Os,
                                                const unsigned short* __restrict__ Wt,
                                                const float* __restrict__ bias,
                                                const float* __restrict__ snorm) {
  __shared__ unsigned short Bl[8 * 8 * 64 * 8];   // [ks][ct][lane][8] = 64 KB
  int t = threadIdx.x;
#pragma unroll
  for (int i = 0; i < 16; i++) {
    int p = t + 256 * i;                  // 0..4095 frag-pieces
    int ks = p >> 9, ct = (p >> 6) & 7, ln = p & 63;
    int pfr = ln & 15, pfk = ln >> 4;
    const unsigned short* srcp = Wt + (size_t)(ct * 16 + pfr) * 256 + ks * 32 + pfk * 8;
    *(uint4*)(Bl + (size_t)p * 8) = *(const uint4*)srcp;
  }
  __syncthreads();

  int lane = t & 63, w = t >> 6;
  int fr = lane & 15, fkg = lane >> 4;
  int row0 = blockIdx.x * 256 + w * 64;

  f32x4 acc[4][8] = {};
#pragma unroll
  for (int ks = 0; ks < 8; ks++) {
    const unsigned short* base = (ks < 4) ? Hs : Csb;
    size_t sbase = (size_t)((ks & 3) * 2 + (fkg >> 1)) * SL16 + (fkg & 1) * 8;
    bf16x8 a[4];
#pragma unroll
    for (int rt = 0; rt < 4; rt++) {
      int row = row0 + rt * 16 + fr;
      a[rt] = *(const bf16x8*)(base + sbase + (size_t)row * 16);
    }
#pragma unroll
    for (int ct = 0; ct < 8; ct++) {
      bf16x8 b = *(const bf16x8*)(Bl + (size_t)((ks * 8 + ct) * 64 + lane) * 8);
#pragma unroll
      for (int rt = 0; rt < 4; rt++)
        acc[rt][ct] = __builtin_amdgcn_mfma_f32_16x16x32_bf16(a[rt], b, acc[rt][ct], 0, 0, 0);
    }
  }

  // epilogue: relu(+bias)*snorm + residual; paired-uint slice-major IO
#pragma unroll
  for (int rt = 0; rt < 4; rt++) {
#pragma unroll
    for (int r = 0; r < 4; r++) {
      int row = row0 + rt * 16 + fkg * 4 + r;
      float sn = snorm[row];
#pragma unroll
      for (int ct = 0; ct < 8; ct++) {
        float v = acc[rt][ct][r];
        float v2 = __shfl_xor(v, 1, 64);
        if (!(lane & 1)) {
          size_t off = (size_t)ct * SL16 + (size_t)row * 16 + fr;
          uint hp = *(const uint*)(Hs + off);
          float2 bv = *(const float2*)(bias + ct * 16 + fr);
          float o1 = fmaxf(v + bv.x, 0.f) * sn + blo(hp);
          float o2 = fmaxf(v2 + bv.y, 0.f) * sn + bhi(hp);
          __builtin_nontemporal_store(pack2(o1, o2), (uint*)(Os + off));
        }
      }
    }
  }
}

// ---------------- readout ----------------
__global__ void k_wcombo(const float* __restrict__ W_ro, const float* __restrict__ W_pred,
                         float* __restrict__ wcv) {
  int i = threadIdx.x;  // 128
  float a = 0.f;
  for (int j = 0; j < HD; j++) a += W_ro[i * HD + j] * W_pred[j];
  wcv[i] = a;
}

__global__ void k_readout(const uint* __restrict__ Hs, const float* __restrict__ wcv,
                          const int* __restrict__ gid, const float* __restrict__ inv_gcnt,
                          float* __restrict__ out) {
  int wave = threadIdx.x >> 6, lane = threadIdx.x & 63;
  int v = blockIdx.x * 4 + wave;
  uint x = Hs[(size_t)(lane >> 3) * SLU + (size_t)v * 8 + (lane & 7)];
  float2 wv = *(const float2*)(wcv + lane * 2);
  float p = blo(x) * wv.x + bhi(x) * wv.y;
#pragma unroll
  for (int o = 32; o > 0; o >>= 1) p += __shfl_down(p, o, 64);
  if (lane == 0) {
    int g = gid[v];
    atomicAdd(&out[g], p * inv_gcnt[g]);
  }
}

// ---------------- launch ----------------
extern "C" void kernel_launch(void* const* d_in, const int* in_sizes, int n_in,
                              void* d_out, int out_size, void* d_ws, size_t ws_size,
                              hipStream_t stream) {
  const float* h      = (const float*)d_in[0];
  const float* snorm  = (const float*)d_in[1];
  const float* W_emb  = (const float*)d_in[2];
  const float* W_node = (const float*)d_in[3];
  const float* b_node = (const float*)d_in[4];
  const float* W_ro   = (const float*)d_in[5];
  const float* W_pred = (const float*)d_in[6];
  const float* b_pred = (const float*)d_in[7];
  const int*   src    = (const int*)d_in[8];
  const int*   dst    = (const int*)d_in[9];
  const int*   gid    = (const int*)d_in[10];
  float* out = (float*)d_out;

  char* ws = (char*)d_ws;
  unsigned short* Xs   = (unsigned short*)(ws + OFF_XB);
  unsigned short* Ys   = (unsigned short*)(ws + OFF_YB);
  unsigned short* Cb   = (unsigned short*)(ws + OFF_CB);
  int*   esrc     = (int*)(ws + OFF_ESRC);
  int*   deg      = (int*)(ws + OFF_DEG);
  int*   gcnt     = (int*)(ws + OFF_GCNT);
  int*   row_s    = (int*)(ws + OFF_ROW);
  float* inv_deg  = (float*)(ws + OFF_IDEG);
  float* inv_gcnt = (float*)(ws + OFF_IGC);
  int*   bsum     = (int*)(ws + OFF_BSUM);
  int*   coff     = (int*)(ws + OFF_COFF);
  float* wcv      = (float*)(ws + OFF_WC);
  unsigned short* Wnt = (unsigned short*)(ws + OFF_WNT);
  uint*  ebuf     = (uint*)(ws + OFF_EBUF);
  int*   gcur     = (int*)(ws + OFF_GCUR);
  unsigned short* Wet = (unsigned short*)(ws + OFF_WET);

  hipMemsetAsync(ws + OFF_GCNT, 0, (size_t)NG * 4, stream);

  k_binit<<<1, NB, 0, stream>>>(gcur);
  k_bin<<<NE / 4096, 256, 0, stream>>>(src, dst, gcur, ebuf);
  k_deg<<<NB, 256, 0, stream>>>(gcur, ebuf, deg);
  k_scan1<<<NN / 1024, 256, 0, stream>>>(deg, bsum);
  k_scan2<<<1, 128, 0, stream>>>(bsum, coff);
  k_scan3<<<NN / 1024, 256, 0, stream>>>(deg, coff, row_s, inv_deg);
  k_place2<<<NB, 256, 0, stream>>>(gcur, ebuf, row_s, esrc);
  k_ghist<<<NN / 256, 256, 0, stream>>>(gid, gcnt);
  k_ginit<<<NG / 256, 256, 0, stream>>>(gcnt, inv_gcnt, out, b_pred);
  k_wprep<<<(NL * 256 * HD) / 256, 256, 0, stream>>>(W_node, Wnt);
  k_weprep<<<(HD * 32) / 256, 256, 0, stream>>>(W_emb, Wet);

  k_embed<<<NN / 64, 256, 0, stream>>>(h, Wet, Xs);

  for (int l = 0; l < NL; l++) {
    unsigned short* hb = (l & 1) ? Ys : Xs;
    unsigned short* ho = (l & 1) ? Xs : Ys;
    k_aggs<<<8 * (NN / 512), 256, 0, stream>>>((const uint*)hb, row_s, deg, esrc,
                                               inv_deg, (uint*)Cb);
    k_apply2<<<NN / 256, 256, 0, stream>>>(hb, Cb, ho, Wnt + (size_t)l * HD * 256,
                                           b_node + (size_t)l * HD, snorm);
  }
  // final h is in Xs after 4 layers (X->Y->X->Y->X)

  k_wcombo<<<1, 128, 0, stream>>>(W_ro, W_pred, wcv);
  k_readout<<<NN / 4, 256, 0, stream>>>((const uint*)Xs, wcv, gid, inv_gcnt, out);
}

// Round 8
// 714.049 us; speedup vs baseline: 2.4022x; 2.4022x over previous
//
#include <hip/hip_runtime.h>

// Problem constants
constexpr int NN  = 131072;   // nodes
constexpr int NE  = 2097152;  // edges
constexpr int HD  = 128;      // hidden
constexpr int NG  = 8192;     // graphs
constexpr int NA  = 28;       // atom types
constexpr int NL  = 4;        // layers

// CSR bucketing
constexpr int NB   = 256;     // buckets
constexpr int BSH  = 9;       // dst>>9 -> bucket (512 nodes/bucket)
constexpr int BNOD = 512;     // nodes per bucket
constexpr int CAP  = 10240;   // slots per bucket (mean 8192 + 22 sigma)

// ---------------- workspace layout (bytes) ----------------
constexpr size_t SZ_FB   = (size_t)NN * HD * 2;          // 32 MiB bf16 feature buf
constexpr size_t OFF_XB   = 0;
constexpr size_t OFF_YB   = OFF_XB + SZ_FB;
constexpr size_t OFF_ESRC = OFF_YB + SZ_FB;
constexpr size_t OFF_DEG  = OFF_ESRC + (size_t)NE * 4;
constexpr size_t OFF_GCNT = OFF_DEG + (size_t)NN * 4;
constexpr size_t OFF_ROW  = OFF_GCNT + (size_t)NG * 4;
constexpr size_t OFF_IDEG = OFF_ROW + (size_t)NN * 4;
constexpr size_t OFF_IGC  = OFF_IDEG + (size_t)NN * 4;
constexpr size_t OFF_BSUM = OFF_IGC + (size_t)NG * 4;
constexpr size_t OFF_COFF = OFF_BSUM + 512;
constexpr size_t OFF_WC   = OFF_COFF + 512;
constexpr size_t OFF_WNT  = OFF_WC + 512;                // bf16 W transposed [L][128][256]
constexpr size_t OFF_EBUF = OFF_WNT + (size_t)NL * HD * 256 * 2;
constexpr size_t OFF_GCUR = OFF_EBUF + (size_t)NB * CAP * 4;
constexpr size_t OFF_WET  = OFF_GCUR + (size_t)NB * 4;   // bf16 W_emb^T [128][32]

// ---------------- bf16 helpers ----------------
__device__ __forceinline__ float blo(uint x) { return __uint_as_float(x << 16); }
__device__ __forceinline__ float bhi(uint x) { return __uint_as_float(x & 0xFFFF0000u); }
__device__ __forceinline__ unsigned short f2b(float f) {
  uint u = __float_as_uint(f);
  return (unsigned short)((u + 0x7FFFu + ((u >> 16) & 1u)) >> 16);
}
__device__ __forceinline__ uint pack2(float a, float b) {
  uint ua = __float_as_uint(a), ub = __float_as_uint(b);
  uint lo = (ua + 0x7FFFu + ((ua >> 16) & 1u)) >> 16;
  uint hi = (ub + 0x7FFFu + ((ub >> 16) & 1u)) & 0xFFFF0000u;
  return lo | hi;
}

typedef __attribute__((ext_vector_type(8))) short bf16x8;
typedef __attribute__((ext_vector_type(4))) float f32x4;

// ---------------- CSR build: bucketed ----------------
__global__ void k_binit(int* __restrict__ gcur) {
  int b = threadIdx.x;           // 256
  gcur[b] = b * CAP;
}

// partition edges into NB buckets by dst>>BSH; packed = (dst&511)<<17 | src
__global__ __launch_bounds__(256) void k_bin(const int* __restrict__ src,
                                             const int* __restrict__ dst,
                                             int* __restrict__ gcur,
                                             uint* __restrict__ ebuf) {
  __shared__ int cnt[NB];
  __shared__ int gbase[NB];
  int t = threadIdx.x;
  cnt[t] = 0;
  int es[16], ed[16];
  int base = blockIdx.x * 4096 + t;
#pragma unroll
  for (int j = 0; j < 16; j++) {
    es[j] = src[base + j * 256];
    ed[j] = dst[base + j * 256];
  }
  __syncthreads();
#pragma unroll
  for (int j = 0; j < 16; j++) atomicAdd(&cnt[ed[j] >> BSH], 1);
  __syncthreads();
  int c = cnt[t];
  if (c > 0) gbase[t] = atomicAdd(&gcur[t], c);
  cnt[t] = 0;
  __syncthreads();
#pragma unroll
  for (int j = 0; j < 16; j++) {
    int b = ed[j] >> BSH;
    int r = atomicAdd(&cnt[b], 1);
    ebuf[(size_t)gbase[b] + r] = ((uint)(ed[j] & (BNOD - 1)) << 17) | (uint)es[j];
  }
}

// per-bucket degree histogram (LDS), coalesced deg writes, no global atomics
__global__ __launch_bounds__(256) void k_deg(const int* __restrict__ gcur,
                                             const uint* __restrict__ ebuf,
                                             int* __restrict__ deg) {
  __shared__ int h[BNOD];
  int b = blockIdx.x, t = threadIdx.x;
  h[t] = 0; h[t + 256] = 0;
  int n = gcur[b] - b * CAP;
  __syncthreads();
  const uint* eb = ebuf + (size_t)b * CAP;
  for (int i = t; i < n; i += 256) atomicAdd(&h[eb[i] >> 17], 1);
  __syncthreads();
  deg[b * BNOD + t] = h[t];
  deg[b * BNOD + t + 256] = h[t + 256];
}

__global__ void k_scan1(const int* __restrict__ deg, int* __restrict__ bsum) {
  __shared__ int s[256];
  int b = blockIdx.x, t = threadIdx.x;
  const int4* p = (const int4*)(deg + (size_t)b * 1024);
  int4 v = p[t];
  s[t] = v.x + v.y + v.z + v.w;
  __syncthreads();
  for (int o = 128; o > 0; o >>= 1) {
    if (t < o) s[t] += s[t + o];
    __syncthreads();
  }
  if (t == 0) bsum[b] = s[0];
}

__global__ void k_scan2(const int* __restrict__ bsum, int* __restrict__ coff) {
  __shared__ int s[128];
  int t = threadIdx.x;
  int mine = bsum[t];
  s[t] = mine;
  __syncthreads();
  for (int o = 1; o < 128; o <<= 1) {
    int v = (t >= o) ? s[t - o] : 0;
    __syncthreads();
    s[t] += v;
    __syncthreads();
  }
  coff[t] = s[t] - mine;  // exclusive
}

__global__ void k_scan3(const int* __restrict__ deg, const int* __restrict__ coff,
                        int* __restrict__ row_start, float* __restrict__ inv_deg) {
  __shared__ int s[256];
  int b = blockIdx.x, t = threadIdx.x;
  int base = b * 1024 + t * 4;
  const int4* p = (const int4*)(deg + base);
  int4 d = *p;
  int lsum = d.x + d.y + d.z + d.w;
  s[t] = lsum;
  __syncthreads();
  for (int o = 1; o < 256; o <<= 1) {
    int v = (t >= o) ? s[t - o] : 0;
    __syncthreads();
    s[t] += v;
    __syncthreads();
  }
  int pre = coff[b] + s[t] - lsum;
  int r0 = pre, r1 = r0 + d.x, r2 = r1 + d.y, r3 = r2 + d.z;
  row_start[base] = r0;  row_start[base + 1] = r1;
  row_start[base + 2] = r2;  row_start[base + 3] = r3;
  inv_deg[base]     = 1.0f / fmaxf((float)d.x, 1.0f);
  inv_deg[base + 1] = 1.0f / fmaxf((float)d.y, 1.0f);
  inv_deg[base + 2] = 1.0f / fmaxf((float)d.z, 1.0f);
  inv_deg[base + 3] = 1.0f / fmaxf((float)d.w, 1.0f);
}

// per-bucket placement: LDS cursors, esrc writes land in a 32KB window
__global__ __launch_bounds__(256) void k_place2(const int* __restrict__ gcur,
                                                const uint* __restrict__ ebuf,
                                                const int* __restrict__ row_start,
                                                int* __restrict__ esrc) {
  __shared__ int cur[BNOD];
  int b = blockIdx.x, t = threadIdx.x;
  cur[t] = row_start[b * BNOD + t];
  cur[t + 256] = row_start[b * BNOD + t + 256];
  int n = gcur[b] - b * CAP;
  __syncthreads();
  const uint* eb = ebuf + (size_t)b * CAP;
  for (int i = t; i < n; i += 256) {
    uint p = eb[i];
    int r = atomicAdd(&cur[p >> 17], 1);
    esrc[r] = (int)(p & 0x1FFFFu);
  }
}

__global__ void k_ghist(const int* __restrict__ gid, int* __restrict__ gcnt) {
  int i = blockIdx.x * blockDim.x + threadIdx.x;
  if (i < NN) atomicAdd(&gcnt[gid[i]], 1);
}

__global__ void k_ginit(const int* __restrict__ gcnt, float* __restrict__ inv_gcnt,
                        float* __restrict__ out, const float* __restrict__ b_pred) {
  int g = blockIdx.x * blockDim.x + threadIdx.x;
  if (g < NG) {
    inv_gcnt[g] = 1.0f / fmaxf((float)gcnt[g], 1.0f);
    out[g] = b_pred[0];
  }
}

// ---------------- weight prep ----------------
// Wnt[l][c][k] = bf16(W_node[l][k][c])
__global__ void k_wprep(const float* __restrict__ Wn, unsigned short* __restrict__ Wnt) {
  int i = blockIdx.x * 256 + threadIdx.x;   // L*256*128 total
  int l = i >> 15;
  int k = (i >> 7) & 255;
  int c = i & 127;
  float v = Wn[((size_t)l * 256 + k) * HD + c];
  Wnt[((size_t)l * HD + c) * 256 + k] = f2b(v);
}

// Wet[c][k] = bf16(W_emb[k][c]), k padded 28->32 with zeros
__global__ void k_weprep(const float* __restrict__ We, unsigned short* __restrict__ Wet) {
  int i = blockIdx.x * 256 + threadIdx.x;   // 128*32 = 4096 total
  int col = i >> 5, k = i & 31;
  Wet[i] = (k < NA) ? f2b(We[(size_t)k * HD + col]) : (unsigned short)0;
}

// ---------------- embedding (MFMA): Xb = bf16(h @ W_emb) ----------------
// block: 64 rows x 128 cols, 4 waves 2x2; K=32 (padded from 28)
__global__ __launch_bounds__(256) void k_embed(const float* __restrict__ h,
                                               const unsigned short* __restrict__ Wet,
                                               unsigned short* __restrict__ Xb) {
  int t = threadIdx.x;
  int lane = t & 63, w = t >> 6;
  int wr = w >> 1, wc = w & 1;
  int row0 = blockIdx.x * 64 + wr * 32;
  int col0 = wc * 64;
  int fr = lane & 15;
  int fk = (lane >> 4) * 8;

  f32x4 acc[2][4] = {};
  bf16x8 a[2];
#pragma unroll
  for (int rt = 0; rt < 2; rt++) {
    int row = row0 + rt * 16 + fr;
    const float* hp = h + (size_t)row * NA + fk;
    float4 p = *(const float4*)hp;                    // k = fk..fk+3 (always < 28)
    float4 q = make_float4(0.f, 0.f, 0.f, 0.f);
    if (fk < 24) q = *(const float4*)(hp + 4);        // k = fk+4..fk+7; fk==24 -> pad 0
    a[rt][0] = (short)f2b(p.x); a[rt][1] = (short)f2b(p.y);
    a[rt][2] = (short)f2b(p.z); a[rt][3] = (short)f2b(p.w);
    a[rt][4] = (short)f2b(q.x); a[rt][5] = (short)f2b(q.y);
    a[rt][6] = (short)f2b(q.z); a[rt][7] = (short)f2b(q.w);
  }
#pragma unroll
  for (int ct = 0; ct < 4; ct++) {
    int col = col0 + ct * 16 + fr;
    bf16x8 b = *(const bf16x8*)(Wet + (size_t)col * 32 + fk);
#pragma unroll
    for (int rt = 0; rt < 2; rt++)
      acc[rt][ct] = __builtin_amdgcn_mfma_f32_16x16x32_bf16(a[rt], b, acc[rt][ct], 0, 0, 0);
  }
  int oc = lane & 15, orb = (lane >> 4) * 4;
#pragma unroll
  for (int rt = 0; rt < 2; rt++) {
#pragma unroll
    for (int ct = 0; ct < 4; ct++) {
      int col = col0 + ct * 16 + oc;
#pragma unroll
      for (int r = 0; r < 4; r++) {
        int row = row0 + rt * 16 + orb + r;
        Xb[(size_t)row * HD + col] = f2b(acc[rt][ct][r]);
      }
    }
  }
}

// ---------------- aggregation: Cb[v] = bf16(mean_{u->v} Hb[u]) ----------------
// one wave per node; 32 lanes cover a 256B row (uint2/lane); 2 edges per load
// instruction via lane-half select; 8 loads (16 edges) in flight
__global__ __launch_bounds__(256) void k_agg(const uint2* __restrict__ H64,
                      const int* __restrict__ row_start, const int* __restrict__ deg,
                      const int* __restrict__ esrc, const float* __restrict__ inv_deg,
                      uint2* __restrict__ C64) {
  int v = blockIdx.x * 4 + (threadIdx.x >> 6);
  int lane = threadIdx.x & 63;
  int half = lane >> 5;
  int cl = lane & 31;                       // cols cl*4 .. cl*4+3
  int rs = __builtin_amdgcn_readfirstlane(row_start[v]);
  int d  = __builtin_amdgcn_readfirstlane(deg[v]);
  float a0 = 0.f, a1 = 0.f, a2 = 0.f, a3 = 0.f;
  float b0 = 0.f, b1 = 0.f, b2 = 0.f, b3 = 0.f;
  int e = 0;
  for (; e + 16 <= d; e += 16) {
    uint2 x[8];
#pragma unroll
    for (int j = 0; j < 8; j++) {
      int ea = esrc[rs + e + 2 * j];        // scalar loads (uniform addr)
      int eb = esrc[rs + e + 2 * j + 1];
      int idx = half ? eb : ea;
      x[j] = H64[(size_t)idx * 32 + cl];
    }
#pragma unroll
    for (int j = 0; j < 8; j++) {
      if (j & 1) { b0 += blo(x[j].x); b1 += bhi(x[j].x); b2 += blo(x[j].y); b3 += bhi(x[j].y); }
      else       { a0 += blo(x[j].x); a1 += bhi(x[j].x); a2 += blo(x[j].y); a3 += bhi(x[j].y); }
    }
  }
  for (; e + 2 <= d; e += 2) {
    int ea = esrc[rs + e], eb = esrc[rs + e + 1];
    int idx = half ? eb : ea;
    uint2 x = H64[(size_t)idx * 32 + cl];
    b0 += blo(x.x); b1 += bhi(x.x); b2 += blo(x.y); b3 += bhi(x.y);
  }
  if (e < d) {
    int idx = esrc[rs + e];
    uint2 x = H64[(size_t)idx * 32 + cl];
    if (half == 0) { a0 += blo(x.x); a1 += bhi(x.x); a2 += blo(x.y); a3 += bhi(x.y); }
  }
  a0 += b0; a1 += b1; a2 += b2; a3 += b3;
  a0 += __shfl_xor(a0, 32, 64);
  a1 += __shfl_xor(a1, 32, 64);
  a2 += __shfl_xor(a2, 32, 64);
  a3 += __shfl_xor(a3, 32, 64);
  float id = inv_deg[v];
  if (half == 0) {
    uint2 o;
    o.x = pack2(a0 * id, a1 * id);
    o.y = pack2(a2 * id, a3 * id);
    C64[(size_t)v * 32 + cl] = o;
  }
}

// ---------------- NodeApply (MFMA, swapped operands): ----------------
// Cio <- bf16(relu([Hb||Cio]@W + b)*snorm + Hb), computed as O^T = W^T-frag x H-frag
// so each lane owns ONE node (col=lane&15) and 4 consecutive out-channels
// ((lane>>4)*4 + r). Epilogue is per-lane uint2 (4xbf16) vector IO, no barrier.
// block: 128 nodes, 4 waves x 32 nodes (2 node-tiles of 16).
__global__ __launch_bounds__(256) void k_apply(const unsigned short* __restrict__ Hb,
                                               unsigned short* __restrict__ Cio,
                                               const unsigned short* __restrict__ Wt,
                                               const float* __restrict__ bias,
                                               const float* __restrict__ snorm) {
  int t = threadIdx.x;
  int lane = t & 63, w = t >> 6;
  int fr = lane & 15, fkg = lane >> 4;
  int n0 = blockIdx.x * 128 + w * 32;       // wave's 32 nodes (2 tiles)

  f32x4 acc[2][8] = {};                     // [node-tile][channel-tile]
#pragma unroll
  for (int ks = 0; ks < 8; ks++) {
    int kb = ks * 32 + fkg * 8;             // 0..255
    bf16x8 aH[2];
#pragma unroll
    for (int nt = 0; nt < 2; nt++) {
      int node = n0 + nt * 16 + fr;
      const unsigned short* ap = (kb < HD)
          ? (Hb  + (size_t)node * HD + kb)
          : (Cio + (size_t)node * HD + (kb - HD));
      aH[nt] = *(const bf16x8*)ap;
    }
#pragma unroll
    for (int ct = 0; ct < 8; ct++) {
      bf16x8 bW = *(const bf16x8*)(Wt + (size_t)(ct * 16 + fr) * 256 + ks * 32 + fkg * 8);
#pragma unroll
      for (int nt = 0; nt < 2; nt++)
        acc[nt][ct] = __builtin_amdgcn_mfma_f32_16x16x32_bf16(bW, aH[nt], acc[nt][ct], 0, 0, 0);
    }
  }

  // epilogue: D[ch][node]; lane -> node = n0+nt*16+fr, chans c0..c0+3
#pragma unroll
  for (int nt = 0; nt < 2; nt++) {
    int node = n0 + nt * 16 + fr;
    float sn = snorm[node];
#pragma unroll
    for (int ct = 0; ct < 8; ct++) {
      int c0 = ct * 16 + fkg * 4;
      float4 bv = *(const float4*)(bias + c0);
      uint2 hp = *(const uint2*)(Hb + (size_t)node * HD + c0);
      float o0 = fmaxf(acc[nt][ct][0] + bv.x, 0.f) * sn + blo(hp.x);
      float o1 = fmaxf(acc[nt][ct][1] + bv.y, 0.f) * sn + bhi(hp.x);
      float o2 = fmaxf(acc[nt][ct][2] + bv.z, 0.f) * sn + blo(hp.y);
      float o3 = fmaxf(acc[nt][ct][3] + bv.w, 0.f) * sn + bhi(hp.y);
      uint2 o;
      o.x = pack2(o0, o1);
      o.y = pack2(o2, o3);
      *(uint2*)(Cio + (size_t)node * HD + c0) = o;
    }
  }
}

// ---------------- readout ----------------
__global__ void k_wcombo(const float* __restrict__ W_ro, const float* __restrict__ W_pred,
                         float* __restrict__ wcv) {
  int i = threadIdx.x;  // 128
  float a = 0.f;
  for (int j = 0; j < HD; j++) a += W_ro[i * HD + j] * W_pred[j];
  wcv[i] = a;
}

__global__ void k_readout(const uint* __restrict__ H32, const float* __restrict__ wcv,
                          const int* __restrict__ gid, const float* __restrict__ inv_gcnt,
                          float* __restrict__ out) {
  int wave = threadIdx.x >> 6, lane = threadIdx.x & 63;
  int v = blockIdx.x * 4 + wave;
  uint x = H32[(size_t)v * 64 + lane];
  float2 wv = *(const float2*)(wcv + lane * 2);
  float p = blo(x) * wv.x + bhi(x) * wv.y;
#pragma unroll
  for (int o = 32; o > 0; o >>= 1) p += __shfl_down(p, o, 64);
  if (lane == 0) {
    int g = gid[v];
    atomicAdd(&out[g], p * inv_gcnt[g]);
  }
}

// ---------------- launch ----------------
extern "C" void kernel_launch(void* const* d_in, const int* in_sizes, int n_in,
                              void* d_out, int out_size, void* d_ws, size_t ws_size,
                              hipStream_t stream) {
  const float* h      = (const float*)d_in[0];
  const float* snorm  = (const float*)d_in[1];
  const float* W_emb  = (const float*)d_in[2];
  const float* W_node = (const float*)d_in[3];
  const float* b_node = (const float*)d_in[4];
  const float* W_ro   = (const float*)d_in[5];
  const float* W_pred = (const float*)d_in[6];
  const float* b_pred = (const float*)d_in[7];
  const int*   src    = (const int*)d_in[8];
  const int*   dst    = (const int*)d_in[9];
  const int*   gid    = (const int*)d_in[10];
  float* out = (float*)d_out;

  char* ws = (char*)d_ws;
  unsigned short* Xb   = (unsigned short*)(ws + OFF_XB);
  unsigned short* Yb   = (unsigned short*)(ws + OFF_YB);
  int*   esrc     = (int*)(ws + OFF_ESRC);
  int*   deg      = (int*)(ws + OFF_DEG);
  int*   gcnt     = (int*)(ws + OFF_GCNT);
  int*   row_s    = (int*)(ws + OFF_ROW);
  float* inv_deg  = (float*)(ws + OFF_IDEG);
  float* inv_gcnt = (float*)(ws + OFF_IGC);
  int*   bsum     = (int*)(ws + OFF_BSUM);
  int*   coff     = (int*)(ws + OFF_COFF);
  float* wcv      = (float*)(ws + OFF_WC);
  unsigned short* Wnt = (unsigned short*)(ws + OFF_WNT);
  uint*  ebuf     = (uint*)(ws + OFF_EBUF);
  int*   gcur     = (int*)(ws + OFF_GCUR);
  unsigned short* Wet = (unsigned short*)(ws + OFF_WET);

  hipMemsetAsync(ws + OFF_GCNT, 0, (size_t)NG * 4, stream);

  k_binit<<<1, NB, 0, stream>>>(gcur);
  k_bin<<<NE / 4096, 256, 0, stream>>>(src, dst, gcur, ebuf);
  k_deg<<<NB, 256, 0, stream>>>(gcur, ebuf, deg);
  k_scan1<<<NN / 1024, 256, 0, stream>>>(deg, bsum);
  k_scan2<<<1, 128, 0, stream>>>(bsum, coff);
  k_scan3<<<NN / 1024, 256, 0, stream>>>(deg, coff, row_s, inv_deg);
  k_place2<<<NB, 256, 0, stream>>>(gcur, ebuf, row_s, esrc);
  k_ghist<<<NN / 256, 256, 0, stream>>>(gid, gcnt);
  k_ginit<<<NG / 256, 256, 0, stream>>>(gcnt, inv_gcnt, out, b_pred);
  k_wprep<<<(NL * 256 * HD) / 256, 256, 0, stream>>>(W_node, Wnt);
  k_weprep<<<(HD * 32) / 256, 256, 0, stream>>>(W_emb, Wet);

  k_embed<<<NN / 64, 256, 0, stream>>>(h, Wet, Xb);

  for (int l = 0; l < NL; l++) {
    unsigned short* hb = (l & 1) ? Yb : Xb;
    unsigned short* cb = (l & 1) ? Xb : Yb;
    k_agg<<<NN / 4, 256, 0, stream>>>((const uint2*)hb, row_s, deg, esrc, inv_deg,
                                      (uint2*)cb);
    k_apply<<<NN / 128, 256, 0, stream>>>(hb, cb, Wnt + (size_t)l * HD * 256,
                                          b_node + (size_t)l * HD, snorm);
  }
  // final h is in Xb after 4 layers

  k_wcombo<<<1, 128, 0, stream>>>(W_ro, W_pred, wcv);
  k_readout<<<NN / 4, 256, 0, stream>>>((const uint*)Xb, wcv, gid, inv_gcnt, out);
}